// Round 3
// baseline (114.462 us; speedup 1.0000x reference)
//
#include <hip/hip_runtime.h>
#include <math.h>

// Problem constants (from reference)
#define MEMN 8
#define WDIM 41      // 1 + DEG*MEM = 1 + 5*8
#define BB   32
#define LL   4096
#define PADN 15      // 2*MEM - 1
#define TILE_T 4     // t-values per block
#define WIN 18       // TILE_T - 1 + PADN  window length per b
#define STRIDE 19    // odd LDS stride (dwords) -> conflict-free over b

// out[b,t,:] = co[t] broadcast;  co[t] = sum_b sum_m xp[b,t+m] * acc_m
// where acc_m = W[m,0] + sum_mm ( W[m,1+5mm]*xp[b,t+m+mm]
//                + W[m,2+5mm] + W[m,3+5mm]*a + W[m,4+5mm]*a^2 + W[m,5+5mm]*a^3 )
// xp[b,j] = x[b, j-15] (zeros for j<15), a = |xp[b, t+m+mm]|.
//
// Thread = (b, t-slot, mq); mq in [0,4) owns m in {2mq, 2mq+1}.
// 512 threads/block, 1024 blocks -> 8192 waves = 8 waves/SIMD.
//
// ROUND-3 FIX: Round 2 spilled (VGPR_Count=32, FETCH 56MB == 524288 thr x 27
// floats x 4B of scratch reads). The zr/zi/a1[9] register arrays are gone;
// operands are read from LDS inside the unrolled loop (conflict-free stride-19,
// measured SQ_LDS_BANK_CONFLICT=0). Live set ~20 VGPRs -> fits the 64-VGPR cap
// of __launch_bounds__(512,8) with zero scratch.

__global__ __launch_bounds__(512, 8)
void gmp_kernel(const float* __restrict__ x,   // (B, L, 2)
                const float* __restrict__ Wr,  // (MEM, WDIM)
                const float* __restrict__ Wi,  // (MEM, WDIM)
                float* __restrict__ out)       // (B, L, 2)
{
    __shared__ float s_re[BB * STRIDE];
    __shared__ float s_im[BB * STRIDE];
    __shared__ float s_am[BB * STRIDE];
    __shared__ float s_part[TILE_T][4][2];   // [t-slot][mq][re/im]

    const int tid = threadIdx.x;
    const int t0  = blockIdx.x * TILE_T;

    // ---- stage x window into LDS: s_*[b*STRIDE + o] = xp[b, t0 + o], o in [0,WIN) ----
    {
        const int o  = tid & 31;   // only o < WIN active
        const int b8 = tid >> 5;   // 0..15
        if (o < WIN) {
            const int g = t0 - PADN + o;   // global t-index into x (max 4094 < LL)
            #pragma unroll
            for (int it = 0; it < 2; ++it) {
                const int b = b8 + 16 * it;
                float re = 0.f, im = 0.f;
                if (g >= 0) {
                    const float2 v = *(const float2*)(x + ((size_t)b * LL + g) * 2);
                    re = v.x; im = v.y;
                }
                s_re[b * STRIDE + o] = re;
                s_im[b * STRIDE + o] = im;
                s_am[b * STRIDE + o] = sqrtf(re * re + im * im);
            }
        }
    }
    __syncthreads();

    // ---- compute: thread = (b, t-slot, mq) ----
    const int b    = tid & 31;
    const int slot = (tid >> 5) & 3;
    const int mq   = tid >> 7;             // 0..3, wave-uniform (W loads stay scalar)
    const int base = b * STRIDE + slot + 2 * mq;

    float cr = 0.f, ci = 0.f;
    #pragma unroll
    for (int ml = 0; ml < 2; ++ml) {
        const int m = 2 * mq + ml;         // wave-uniform
        float ar = Wr[m * WDIM];           // uniform -> s_load
        float ai = Wi[m * WDIM];
        #pragma unroll
        for (int mm = 0; mm < MEMN; ++mm) {
            const int k  = base + ml + mm;      // LDS index for xp[b, t+m+mm]
            const int wb = m * WDIM + 1 + 5 * mm;
            const float xr = s_re[k];
            const float xi = s_im[k];
            const float v1 = s_am[k];
            const float v2 = v1 * v1;
            const float v3 = v2 * v1;
            const float w0r = Wr[wb], w0i = Wi[wb];
            // c=0 channel: W * xp  (complex * complex)
            ar += w0r * xr - w0i * xi;
            ai += w0r * xi + w0i * xr;
            // c=1..4: cubic polynomial in amp (complex coeffs, real var)
            ar += Wr[wb + 1] + Wr[wb + 2] * v1 + Wr[wb + 3] * v2 + Wr[wb + 4] * v3;
            ai += Wi[wb + 1] + Wi[wb + 2] * v1 + Wi[wb + 3] * v2 + Wi[wb + 4] * v3;
        }
        // contrib += xp[b,t+m] * acc_m  (complex * complex)
        const float zr0 = s_re[base + ml];
        const float zi0 = s_im[base + ml];
        cr += zr0 * ar - zi0 * ai;
        ci += zr0 * ai + zi0 * ar;
    }

    // ---- butterfly reduce over b (32-lane halves of each wave) ----
    #pragma unroll
    for (int mask = 16; mask >= 1; mask >>= 1) {
        cr += __shfl_xor(cr, mask, 64);
        ci += __shfl_xor(ci, mask, 64);
    }
    if (b == 0) {
        s_part[slot][mq][0] = cr;
        s_part[slot][mq][1] = ci;
    }
    __syncthreads();

    // ---- combine mq partials + broadcast write: out[b'][t0+j][:] ----
    if (tid < BB * TILE_T) {
        const int j  = tid & (TILE_T - 1);  // 0..3
        const int bw = tid >> 2;            // 0..31
        float2 v;
        v.x = s_part[j][0][0] + s_part[j][1][0] + s_part[j][2][0] + s_part[j][3][0];
        v.y = s_part[j][0][1] + s_part[j][1][1] + s_part[j][2][1] + s_part[j][3][1];
        *(float2*)(out + ((size_t)bw * LL + t0 + j) * 2) = v;
    }
}

extern "C" void kernel_launch(void* const* d_in, const int* in_sizes, int n_in,
                              void* d_out, int out_size, void* d_ws, size_t ws_size,
                              hipStream_t stream) {
    const float* x  = (const float*)d_in[0];
    // d_in[1] = h_0 : unused by the reference computation
    const float* Wr = (const float*)d_in[2];
    const float* Wi = (const float*)d_in[3];
    float* out = (float*)d_out;

    gmp_kernel<<<dim3(LL / TILE_T), dim3(512), 0, stream>>>(x, Wr, Wi, out);
}

// Round 4
// 63.940 us; speedup vs baseline: 1.7902x; 1.7902x over previous
//
#include <hip/hip_runtime.h>
#include <math.h>

// Problem constants (from reference)
#define MEMN 8
#define WDIM 41      // 1 + DEG*MEM = 1 + 5*8
#define BB   32
#define LL   4096
#define PADN 15      // 2*MEM - 1
#define TILE_T 4     // t-values per block
#define WIN 18       // TILE_T - 1 + PADN  window length per b
#define STRIDE 19    // odd LDS stride (dwords) -> conflict-free over b

// out[b,t,:] = co[t] broadcast;  co[t] = sum_b sum_m xp[b,t+m] * acc_m
// where acc_m = W[m,0] + sum_mm ( W[m,1+5mm]*xp[b,t+m+mm]
//                + W[m,2+5mm] + W[m,3+5mm]*a + W[m,4+5mm]*a^2 + W[m,5+5mm]*a^3 )
// xp[b,j] = x[b, j-15] (zeros for j<15), a = |xp[b, t+m+mm]|.
//
// Thread = (b, t-slot, mq); mq in [0,4) owns m in {2mq, 2mq+1}.
// 512 threads/block, 1024 blocks -> 8192 waves = 8 waves/SIMD.
//
// ROUND-4 FIX: R2/R3 both spilled identically (VGPR=32, 56MB scratch-read +
// 105MB scratch-write) regardless of register arrays -> the pressure source
// was the ~164 W loads: LLVM treats m = f(tid) as DIVERGENT, so W loads were
// per-lane VMEM, hoisted by the scheduler, blowing the 64-VGPR cap.
// readfirstlane(m) -> SGPR -> uniform pointer -> s_load into SGPRs: W leaves
// the VGPR budget entirely. x-window back in registers (27 floats, read once
// from conflict-free stride-19 LDS).

__global__ __launch_bounds__(512, 8)
void gmp_kernel(const float* __restrict__ x,   // (B, L, 2)
                const float* __restrict__ Wr,  // (MEM, WDIM)
                const float* __restrict__ Wi,  // (MEM, WDIM)
                float* __restrict__ out)       // (B, L, 2)
{
    __shared__ float s_re[BB * STRIDE];
    __shared__ float s_im[BB * STRIDE];
    __shared__ float s_am[BB * STRIDE];
    __shared__ float s_part[TILE_T][4][2];   // [t-slot][mq][re/im]

    const int tid = threadIdx.x;
    const int t0  = blockIdx.x * TILE_T;

    // ---- stage x window into LDS: s_*[b*STRIDE + o] = xp[b, t0 + o], o in [0,WIN) ----
    {
        const int o  = tid & 31;   // only o < WIN active
        const int b8 = tid >> 5;   // 0..15
        if (o < WIN) {
            const int g = t0 - PADN + o;   // global t-index into x (max 4094 < LL)
            #pragma unroll
            for (int it = 0; it < 2; ++it) {
                const int b = b8 + 16 * it;
                float re = 0.f, im = 0.f;
                if (g >= 0) {
                    const float2 v = *(const float2*)(x + ((size_t)b * LL + g) * 2);
                    re = v.x; im = v.y;
                }
                s_re[b * STRIDE + o] = re;
                s_im[b * STRIDE + o] = im;
                s_am[b * STRIDE + o] = sqrtf(re * re + im * im);
            }
        }
    }
    __syncthreads();

    // ---- compute: thread = (b, t-slot, mq) ----
    const int b    = tid & 31;
    const int slot = (tid >> 5) & 3;
    const int mq   = tid >> 7;             // constant across each 64-lane wave
    const int base = b * STRIDE + slot + 2 * mq;

    // x-window registers: k = ml + mm in [0, 8]  (27 VGPRs)
    float zr[9], zi[9], a1[9];
    #pragma unroll
    for (int k = 0; k < 9; ++k) {
        zr[k] = s_re[base + k];
        zi[k] = s_im[base + k];
        a1[k] = s_am[base + k];
    }

    float cr = 0.f, ci = 0.f;
    #pragma unroll
    for (int ml = 0; ml < 2; ++ml) {
        // Force wave-uniformity: SGPR row index -> uniform pointers -> s_load.
        const int m_u = __builtin_amdgcn_readfirstlane(2 * mq + ml);
        const float* __restrict__ WrU = Wr + m_u * WDIM;
        const float* __restrict__ WiU = Wi + m_u * WDIM;
        float ar = WrU[0];                 // s_load_dword
        float ai = WiU[0];
        #pragma unroll
        for (int mm = 0; mm < MEMN; ++mm) {
            const int k  = ml + mm;        // compile-time after unroll
            const int wb = 1 + 5 * mm;     // constant offset from uniform base
            const float v1 = a1[k];
            const float v2 = v1 * v1;
            const float v3 = v2 * v1;
            const float w0r = WrU[wb], w0i = WiU[wb];
            // c=0 channel: W * xp  (complex * complex)
            ar += w0r * zr[k] - w0i * zi[k];
            ai += w0r * zi[k] + w0i * zr[k];
            // c=1..4: cubic polynomial in amp (complex coeffs, real var)
            ar += WrU[wb + 1] + WrU[wb + 2] * v1 + WrU[wb + 3] * v2 + WrU[wb + 4] * v3;
            ai += WiU[wb + 1] + WiU[wb + 2] * v1 + WiU[wb + 3] * v2 + WiU[wb + 4] * v3;
        }
        // contrib += xp[b,t+m] * acc_m  (complex * complex); local index of k=m is ml
        cr += zr[ml] * ar - zi[ml] * ai;
        ci += zr[ml] * ai + zi[ml] * ar;
    }

    // ---- butterfly reduce over b (32-lane halves of each wave) ----
    #pragma unroll
    for (int mask = 16; mask >= 1; mask >>= 1) {
        cr += __shfl_xor(cr, mask, 64);
        ci += __shfl_xor(ci, mask, 64);
    }
    if (b == 0) {
        s_part[slot][mq][0] = cr;
        s_part[slot][mq][1] = ci;
    }
    __syncthreads();

    // ---- combine mq partials + broadcast write: out[b'][t0+j][:] ----
    if (tid < BB * TILE_T) {
        const int j  = tid & (TILE_T - 1);  // 0..3
        const int bw = tid >> 2;            // 0..31
        float2 v;
        v.x = s_part[j][0][0] + s_part[j][1][0] + s_part[j][2][0] + s_part[j][3][0];
        v.y = s_part[j][0][1] + s_part[j][1][1] + s_part[j][2][1] + s_part[j][3][1];
        *(float2*)(out + ((size_t)bw * LL + t0 + j) * 2) = v;
    }
}

extern "C" void kernel_launch(void* const* d_in, const int* in_sizes, int n_in,
                              void* d_out, int out_size, void* d_ws, size_t ws_size,
                              hipStream_t stream) {
    const float* x  = (const float*)d_in[0];
    // d_in[1] = h_0 : unused by the reference computation
    const float* Wr = (const float*)d_in[2];
    const float* Wi = (const float*)d_in[3];
    float* out = (float*)d_out;

    gmp_kernel<<<dim3(LL / TILE_T), dim3(512), 0, stream>>>(x, Wr, Wi, out);
}